// Round 1
// baseline (119122.644 us; speedup 1.0000x reference)
//
#include <hip/hip_runtime.h>
#include <math.h>

#define NV    8192
#define DEG   16
#define EMBD  512
#define NPCC  256
#define NL    257
#define GBLK  32
#define TPB   256

// workspace layout (bytes)
#define WS_CNT   0
#define WS_GEN   128
#define WS_SSQ   256      // 4*32 floats
#define WS_H1    1024     // 512 floats
#define WS_H2    3072     // 512 floats
#define WS_LOG   5120     // 320 floats
#define WS_OHD   6528     // 256 floats
#define WS_EH    8192     // 8192 floats
#define WS_HF    65536    // 8192*512 floats = 16MB

struct __align__(16) Smem {
  float wembT[16*512];   // W[:,kslice] transposed: [kk][i]
  float fc1[16*512];     // fc1_w row slice
  float fc2[16*512];     // fc2_w row slice (padded rows zero)
  float fc3[12*512];     // fc3_w row slice (padded rows/cols zero)
  float woh[256*16];     // W_oh[:, kslice]: [c][kk]
  float ohdot[256];      // dot(W_oh[c], a2)
  float a2[512];
  float newe[512];
  float h1[512];
  float h2[512];
  float logits[320];
  float e[20];
  float attn[20];
  float fc1b[16];
  float fc2b[16];
  float fc3b[16];
  float red[16];
  float scalf[4];        // 0: lpp, 1: reg
  int   scali[4];        // 0: n_used, 1: c_prev
  int   nbrs[16];
  unsigned char colors[NV];  // color+1, 0 = uncolored
};
static_assert(sizeof(Smem) <= 160*1024, "LDS overflow");

__device__ __forceinline__ float dot4(const float4 a, const float4 b) {
  return a.x*b.x + a.y*b.y + a.z*b.z + a.w*b.w;
}
__device__ __forceinline__ float red64_add(float x) {
  #pragma unroll
  for (int off = 1; off < 64; off <<= 1) x += __shfl_xor(x, off, 64);
  return x;
}
__device__ __forceinline__ float red16_add(float x) {
  #pragma unroll
  for (int off = 1; off < 16; off <<= 1) x += __shfl_xor(x, off, 64);
  return x;
}

__device__ __forceinline__ void gbar(unsigned* cnt, unsigned* gen, unsigned ep) {
  __syncthreads();
  if (threadIdx.x == 0) {
    unsigned prev = __hip_atomic_fetch_add(cnt, 1u, __ATOMIC_ACQ_REL, __HIP_MEMORY_SCOPE_AGENT);
    if (prev == ep * GBLK - 1u) {
      __hip_atomic_store(gen, ep, __ATOMIC_RELEASE, __HIP_MEMORY_SCOPE_AGENT);
    } else {
      while (__hip_atomic_load(gen, __ATOMIC_ACQUIRE, __HIP_MEMORY_SCOPE_AGENT) < ep) { }
    }
  }
  __syncthreads();
}

__global__ void __launch_bounds__(TPB, 1)
gc_kernel(const int* __restrict__ adj, const float* __restrict__ W,
          const float* __restrict__ a, const float* __restrict__ fc1w,
          const float* __restrict__ fc1b_g, const float* __restrict__ fc2w,
          const float* __restrict__ fc2b_g, const float* __restrict__ fc3w,
          const float* __restrict__ fc3b_g, const int* __restrict__ basep,
          float* __restrict__ out, unsigned char* __restrict__ ws)
{
  extern __shared__ char smem_raw[];
  Smem& S = *reinterpret_cast<Smem*>(smem_raw);
  const int b    = blockIdx.x;
  const int t    = threadIdx.x;
  const int wave = t >> 6;
  const int lane = t & 63;
  const int g    = lane >> 4;
  const int j16  = lane & 15;

  unsigned* cnt = (unsigned*)(ws + WS_CNT);
  unsigned* gen = (unsigned*)(ws + WS_GEN);
  float* ssqP = (float*)(ws + WS_SSQ);
  float* h1g  = (float*)(ws + WS_H1);
  float* h2g  = (float*)(ws + WS_H2);
  float* logg = (float*)(ws + WS_LOG);
  float* ohdg = (float*)(ws + WS_OHD);
  float* eHg  = (float*)(ws + WS_EH);
  float* HF   = (float*)(ws + WS_HF);

  const int kbase  = b * 16;
  const int nrows2 = (b < 16) ? 13 : 12;
  const int base2  = (b < 16) ? 13*b : 208 + 12*(b-16);
  const int nrows3 = (b == 0) ? 9 : 8;
  const int base3  = (b == 0) ? 0 : 8*b + 1;

  // ================= init =================
  for (int i = t; i < EMBD; i += TPB) S.a2[i] = a[EMBD + i];
  for (int i = t; i < 16*512; i += TPB) S.fc1[i] = fc1w[(size_t)kbase*512 + i];
  for (int i = t; i < 16*512; i += TPB) {
    int rr = i >> 9;
    S.fc2[i] = (rr < nrows2) ? fc2w[(size_t)base2*512 + i] : 0.f;
  }
  for (int i = t; i < 12*512; i += TPB) {
    int rr = i >> 9, cc = i & 511;
    S.fc3[i] = (rr < nrows3 && cc < 400) ? fc3w[(size_t)(base3+rr)*400 + cc] : 0.f;
  }
  for (int i = t; i < 512; i += TPB) {
    const float* src = W + (size_t)i*512 + kbase;
    #pragma unroll
    for (int kk = 0; kk < 16; ++kk) S.wembT[kk*512 + i] = src[kk];
  }
  for (int c = t; c < 256; c += TPB) {
    const float* src = W + (size_t)(512 + c)*512 + kbase;
    #pragma unroll
    for (int kk = 0; kk < 16; ++kk) S.woh[c*16 + kk] = src[kk];
  }
  if (t < 16) {
    S.fc1b[t] = fc1b_g[kbase + t];
    S.fc2b[t] = (t < nrows2) ? fc2b_g[base2 + t] : 0.f;
    S.fc3b[t] = (t < nrows3) ? fc3b_g[base3 + t] : 0.f;
  }
  for (int i = t; i < NV/4; i += TPB) ((int*)S.colors)[i] = 0;
  if (t == 0) {
    S.colors[0] = 1;     // vertex 0: color 0
    S.scali[0] = 1;      // n_used
    S.scali[1] = 0;      // c_prev (color of vertex 0)
    S.scalf[0] = 0.f;    // lpp
  }
  // ohdot slice (8 values per block), from global W and a
  {
    #pragma unroll
    for (int rep = 0; rep < 2; ++rep) {
      int c = b*8 + wave*2 + rep;
      const float* wr = W + (size_t)(512 + c)*512;
      float acc = 0.f;
      #pragma unroll
      for (int p = 0; p < 2; ++p) {
        float4 w4 = *(const float4*)&wr[p*256 + lane*4];
        float4 a4 = *(const float4*)&a[EMBD + p*256 + lane*4];
        acc += dot4(w4, a4);
      }
      acc = red64_add(acc);
      if (lane == 0) ohdg[c] = acc;
    }
  }
  if (b == 0) {
    if (t < 128) *(float4*)&HF[t*4] = make_float4(0.f,0.f,0.f,0.f); // row 0 = He(0) = 0
    if (t == 0) eHg[0] = 0.f;
  }
  __syncthreads();
  // sum-of-squares partials for reg (padded entries are zero)
  {
    float s0=0.f, s1=0.f, s2=0.f, s3=0.f;
    for (int i = t; i < 16*512; i += TPB) {
      float x = S.wembT[i]; s0 += x*x;
      x = S.fc1[i]; s1 += x*x;
      x = S.fc2[i]; s2 += x*x;
    }
    for (int i = t; i < 12*512; i += TPB) { float x = S.fc3[i]; s3 += x*x; }
    for (int i = t; i < 4096; i += TPB)   { float x = S.woh[i]; s0 += x*x; }
    s0 = red64_add(s0); s1 = red64_add(s1); s2 = red64_add(s2); s3 = red64_add(s3);
    if (lane == 0) { S.red[wave*4+0]=s0; S.red[wave*4+1]=s1; S.red[wave*4+2]=s2; S.red[wave*4+3]=s3; }
    __syncthreads();
    if (t == 0) {
      for (int m = 0; m < 4; ++m)
        ssqP[m*GBLK + b] = S.red[m] + S.red[4+m] + S.red[8+m] + S.red[12+m];
    }
  }
  unsigned ep = 1;
  gbar(cnt, gen, ep);
  if (t < 256) S.ohdot[t] = ohdg[t];
  if (b == 0 && t == 0) {
    float reg = 0.f;
    for (int m = 0; m < 4; ++m) {
      float s = 0.f;
      for (int bb = 0; bb < GBLK; ++bb) s += ssqP[m*GBLK + bb];
      reg += sqrtf(s);
    }
    S.scalf[1] = reg;
  }
  __syncthreads();

  // ================= main sequential loop =================
  #pragma unroll 1
  for (int v = 1; v < NV; ++v) {
    const int cprev = S.scali[1];
    const int nused = S.scali[0];

    // ---- phase 1a: neighbor list + raw attention logits ----
    if (t < DEG) {
      int u = adj[v*DEG + t];
      S.nbrs[t] = u;
      float er;
      if (u >= v)           er = 0.f;
      else if (u == v - 1)  er = eHg[u] + S.ohdot[cprev];
      else                  er = eHg[u];
      S.e[t+1] = (er >= 0.f) ? er : 0.2f * er;
    }
    if (t == DEG) S.e[0] = 0.f;
    __syncthreads();

    // ---- phase 1b: softmax over 17 (thread 0) ----
    if (t == 0) {
      float m = -INFINITY;
      #pragma unroll
      for (int j = 0; j <= DEG; ++j) m = fmaxf(m, S.e[j]);
      float ex[DEG+1]; float ssum = 0.f;
      #pragma unroll
      for (int j = 0; j <= DEG; ++j) { ex[j] = expf(S.e[j] - m); ssum += ex[j]; }
      #pragma unroll
      for (int j = 0; j <= DEG; ++j) S.attn[j] = ex[j] / ssum;
    }
    __syncthreads();

    // ---- phase 1c: agg = sum attn_j * h_j ; new_e = elu(agg) ----
    {
      const int c0 = 2*t;
      float2 hv[DEG]; int us[DEG];
      #pragma unroll
      for (int j = 0; j < DEG; ++j) {
        int u = S.nbrs[j];
        us[j] = u;
        float2 ld = *(const float2*)&HF[(size_t)u*EMBD + c0];
        hv[j].x = (u < v) ? ld.x : 0.f;
        hv[j].y = (u < v) ? ld.y : 0.f;
      }
      float acc0 = 0.f, acc1 = 0.f;
      #pragma unroll
      for (int j = 0; j < DEG; ++j) {
        float ax = S.attn[j+1];
        float hx = hv[j].x, hy = hv[j].y;
        if (us[j] == v - 1) {
          const float* wr = W + (size_t)(EMBD + cprev)*EMBD;
          hx += wr[c0]; hy += wr[c0+1];
        }
        acc0 += ax*hx; acc1 += ax*hy;
      }
      S.newe[c0]   = (acc0 > 0.f) ? acc0 : expm1f(acc0);
      S.newe[c0+1] = (acc1 > 0.f) ? acc1 : expm1f(acc1);
    }
    __syncthreads();

    // ---- phase 1d: fc1 slice + He(v) slice ----
    {
      const int r = wave*4 + g;
      float acc = 0.f;
      const float* wrow = S.fc1 + r*512;
      #pragma unroll
      for (int tt = 0; tt < 8; ++tt) {
        float4 x4 = *(const float4*)&S.newe[j16*4 + tt*64];
        float4 w4 = *(const float4*)&wrow[j16*4 + tt*64];
        acc += dot4(x4, w4);
      }
      acc = red16_add(acc);
      if (j16 == 0) {
        float hvv = acc + S.fc1b[r];
        h1g[kbase + r] = (hvv >= 0.f) ? hvv : 0.01f*hvv;
      }
      float acc2 = 0.f;
      const float* w2row = S.wembT + r*512;
      #pragma unroll
      for (int tt = 0; tt < 8; ++tt) {
        float4 x4 = *(const float4*)&S.newe[j16*4 + tt*64];
        float4 w4 = *(const float4*)&w2row[j16*4 + tt*64];
        acc2 += dot4(x4, w4);
      }
      acc2 = red16_add(acc2);
      if (j16 == 0) HF[(size_t)v*EMBD + kbase + r] = acc2;
    }
    ++ep; gbar(cnt, gen, ep);   // barrier A

    // ---- phase 2: fc2 slice; fold Woh into row v-1; eH updates ----
    if (t < 128) *(float4*)&S.h1[t*4] = *(const float4*)&h1g[t*4];
    __syncthreads();
    {
      const int rr = wave*4 + g;
      float acc = 0.f;
      const float* wrow = S.fc2 + rr*512;
      #pragma unroll
      for (int tt = 0; tt < 8; ++tt) {
        float4 x4 = *(const float4*)&S.h1[j16*4 + tt*64];
        float4 w4 = *(const float4*)&wrow[j16*4 + tt*64];
        acc += dot4(x4, w4);
      }
      acc = red16_add(acc);
      if (j16 == 0 && rr < nrows2) {
        float hvv = acc + S.fc2b[rr];
        h2g[base2 + rr] = (hvv >= 0.f) ? hvv : 0.01f*hvv;
      }
    }
    if (wave == 3 && lane < 16)
      HF[(size_t)(v-1)*EMBD + kbase + lane] += S.woh[cprev*16 + lane];
    if (b == 0 && wave == 0) {
      float4 xa = *(const float4*)&HF[(size_t)v*EMBD + lane*4];
      float4 xb = *(const float4*)&HF[(size_t)v*EMBD + 256 + lane*4];
      float4 aa = *(const float4*)&S.a2[lane*4];
      float4 ab = *(const float4*)&S.a2[256 + lane*4];
      float acc = dot4(xa, aa) + dot4(xb, ab);
      acc = red64_add(acc);
      if (lane == 0) {
        eHg[v] = acc;
        eHg[v-1] += S.ohdot[cprev];
      }
    }
    ++ep; gbar(cnt, gen, ep);   // barrier B

    // ---- phase 3: fc3 slice -> logits ----
    if (t < 100)       *(float4*)&S.h2[t*4] = *(const float4*)&h2g[t*4];
    else if (t < 128)  *(float4*)&S.h2[t*4] = make_float4(0.f,0.f,0.f,0.f);
    __syncthreads();
    if (wave < 3) {
      const int rr = wave*4 + g;
      float acc = 0.f;
      const float* wrow = S.fc3 + rr*512;
      #pragma unroll
      for (int tt = 0; tt < 8; ++tt) {
        float4 x4 = *(const float4*)&S.h2[j16*4 + tt*64];
        float4 w4 = *(const float4*)&wrow[j16*4 + tt*64];
        acc += dot4(x4, w4);
      }
      acc = red16_add(acc);
      if (j16 == 0 && rr < nrows3) logg[base3 + rr] = acc + S.fc3b[rr];
    }
    ++ep; gbar(cnt, gen, ep);   // barrier C

    // ---- phase 4: mask + softmax-argmax (redundant, wave 0) ----
    if (wave == 0) {
      int nc[DEG];
      #pragma unroll
      for (int j = 0; j < DEG; ++j) nc[j] = (int)S.colors[S.nbrs[j]] - 1;
      float sv[5];
      float bm = -INFINITY;
      #pragma unroll
      for (int p = 0; p < 5; ++p) {
        int idx = lane + p*64;
        float val = -INFINITY;
        if (idx < NL) {
          val = logg[idx];
          bool msk = (idx >= nused) && (idx < NPCC);
          #pragma unroll
          for (int j = 0; j < DEG; ++j) msk |= (idx == nc[j]);
          if (msk) val = -INFINITY;
        }
        sv[p] = val;
        bm = fmaxf(bm, val);
      }
      #pragma unroll
      for (int off = 1; off < 64; off <<= 1) bm = fmaxf(bm, __shfl_xor(bm, off, 64));
      float ssum = 0.f;
      #pragma unroll
      for (int p = 0; p < 5; ++p) ssum += expf(sv[p] - bm);
      #pragma unroll
      for (int off = 1; off < 64; off <<= 1) ssum += __shfl_xor(ssum, off, 64);
      // argmax over probs (matches reference rounding of exp(x-m)/S)
      float bp = -1.f; int bi = NL + 10;
      #pragma unroll
      for (int p = 0; p < 5; ++p) {
        int idx = lane + p*64;
        float pj = (idx < NL) ? (expf(sv[p] - bm) / ssum) : -1.f;
        if (pj > bp) { bp = pj; bi = idx; }   // ascending idx -> keeps first
      }
      #pragma unroll
      for (int off = 1; off < 64; off <<= 1) {
        float op = __shfl_xor(bp, off, 64);
        int   oi = __shfl_xor(bi, off, 64);
        if (op > bp || (op == bp && oi < bi)) { bp = op; bi = oi; }
      }
      if (lane == 0) {
        int isnew  = (bi == NPCC) ? 1 : 0;
        int chosen = isnew ? nused : bi;
        S.scali[0] = nused + isnew;
        S.scali[1] = chosen;
        S.scalf[0] += logf(bp + 1e-8f) - logf(1e-8f);
        S.colors[v] = (unsigned char)(chosen + 1);
      }
    }
    __syncthreads();
  }

  // ================= output =================
  if (b == 0) {
    for (int i = t; i < NV; i += TPB) out[i] = (float)((int)S.colors[i] - 1);
    if (t == 0) {
      int bv = basep[0];
      int bl = (bv >= -100000 && bv <= 100000) ? bv : (int)__int_as_float(bv);
      float loss = ((float)(S.scali[0] - bl)) * S.scalf[0] / 8192.0f + 0.05f * S.scalf[1];
      out[NV] = loss;
    }
  }
}

extern "C" void kernel_launch(void* const* d_in, const int* in_sizes, int n_in,
                              void* d_out, int out_size, void* d_ws, size_t ws_size,
                              hipStream_t stream) {
  const int*   adj  = (const int*)d_in[0];
  const float* W    = (const float*)d_in[1];
  const float* av   = (const float*)d_in[2];
  const float* f1w  = (const float*)d_in[3];
  const float* f1b  = (const float*)d_in[4];
  const float* f2w  = (const float*)d_in[5];
  const float* f2b  = (const float*)d_in[6];
  const float* f3w  = (const float*)d_in[7];
  const float* f3b  = (const float*)d_in[8];
  const int*   bas  = (const int*)d_in[9];
  float* out = (float*)d_out;
  unsigned char* ws = (unsigned char*)d_ws;

  // zero barrier counters (workspace is poisoned 0xAA before every launch)
  hipMemsetAsync(d_ws, 0, 1024, stream);
  hipFuncSetAttribute((const void*)gc_kernel,
                      hipFuncAttributeMaxDynamicSharedMemorySize,
                      (int)sizeof(Smem));
  gc_kernel<<<dim3(GBLK), dim3(TPB), sizeof(Smem), stream>>>(
      adj, W, av, f1w, f1b, f2w, f2b, f3w, f3b, bas, out, ws);
}

// Round 3
// 81305.542 us; speedup vs baseline: 1.4651x; 1.4651x over previous
//
#include <hip/hip_runtime.h>
#include <math.h>

#define NV    8192
#define DEG   16
#define EMBD  512
#define NPCC  256
#define NL    257
#define GBLK  32
#define TPB   256

// workspace layout (bytes)
#define WS_FLAG  0        // 32 flags, 128B apart (4 KB)
#define WS_SSQ   4096     // 4*32 floats
#define WS_OHD   5120     // 256 floats
#define WS_H1    8192     // 2 x 512 floats (parity)
#define WS_H2    12288    // 2 x 512 floats
#define WS_LOG   16384    // 2 x 512 floats
#define WS_EHP   20480    // 4 x 32 floats (eH partials, parity v&3)
#define WS_EHV   24576    // 8192 floats (eH value incl. ohdot fold)
#define WS_HF    65536    // 8192*512 floats = 16MB (He rows, W_oh folded at D)

struct __align__(16) Smem {
  float wembT[16*512];   // W[:,kslice] transposed: [out][in]
  float fc1[16*512];
  float fc2[16*512];     // padded rows zero
  float fc3[12*512];     // padded rows/cols zero
  float woh[256*16];     // W_oh[:, kslice]
  float ohdot[256];
  float a2[512];
  float newe[512];
  float h1[512];
  float h2[512];
  float logits[512];
  float e[20];
  float attn[20];
  float hev[16];
  float fc1b[16];
  float fc2b[16];
  float fc3b[16];
  float red[16];
  float scalf[4];        // 0: lpp, 1: reg
  int   scali[4];        // 0: n_used
  int   nbrs[4][16];     // parity v&3
  int   runA_sh;
  unsigned char colors[NV];
};
static_assert(sizeof(Smem) <= 160*1024, "LDS overflow");

__device__ __forceinline__ float dot4(const float4 a, const float4 b) {
  return a.x*b.x + a.y*b.y + a.z*b.z + a.w*b.w;
}
__device__ __forceinline__ float red64_add(float x) {
  #pragma unroll
  for (int off = 1; off < 64; off <<= 1) x += __shfl_xor(x, off, 64);
  return x;
}
__device__ __forceinline__ float red16_add(float x) {
  #pragma unroll
  for (int off = 1; off < 16; off <<= 1) x += __shfl_xor(x, off, 64);
  return x;
}

__global__ void __launch_bounds__(TPB, 1)
gc_kernel(const int* __restrict__ adj, const float* __restrict__ W,
          const float* __restrict__ a, const float* __restrict__ fc1w,
          const float* __restrict__ fc1b_g, const float* __restrict__ fc2w,
          const float* __restrict__ fc2b_g, const float* __restrict__ fc3w,
          const float* __restrict__ fc3b_g, const int* __restrict__ basep,
          float* __restrict__ out, unsigned char* __restrict__ ws)
{
  extern __shared__ char smem_raw[];
  Smem& S = *reinterpret_cast<Smem*>(smem_raw);
  const int b    = blockIdx.x;
  const int t    = threadIdx.x;
  const int wave = t >> 6;
  const int lane = t & 63;
  const int g    = lane >> 4;
  const int j16  = lane & 15;

  unsigned* flags = (unsigned*)(ws + WS_FLAG);
  float* ssqP  = (float*)(ws + WS_SSQ);
  float* ohdg  = (float*)(ws + WS_OHD);
  float* h1g   = (float*)(ws + WS_H1);
  float* h2g   = (float*)(ws + WS_H2);
  float* logg  = (float*)(ws + WS_LOG);
  float* eHpg  = (float*)(ws + WS_EHP);
  float* eHvg  = (float*)(ws + WS_EHV);
  float* HF    = (float*)(ws + WS_HF);

  const int kbase  = b * 16;
  const int nrows2 = (b < 16) ? 13 : 12;
  const int base2  = (b < 16) ? 13*b : 208 + 12*(b-16);
  const int nrows3 = (b == 0) ? 9 : 8;
  const int base3  = (b == 0) ? 0 : 8*b + 1;

  // ================= init =================
  for (int i = t; i < EMBD; i += TPB) S.a2[i] = a[EMBD + i];
  for (int i = t; i < 16*512; i += TPB) S.fc1[i] = fc1w[(size_t)kbase*512 + i];
  for (int i = t; i < 16*512; i += TPB) {
    int rr = i >> 9;
    S.fc2[i] = (rr < nrows2) ? fc2w[(size_t)base2*512 + i] : 0.f;
  }
  for (int i = t; i < 12*512; i += TPB) {
    int rr = i >> 9, cc = i & 511;
    S.fc3[i] = (rr < nrows3 && cc < 400) ? fc3w[(size_t)(base3+rr)*400 + cc] : 0.f;
  }
  for (int i = t; i < 512; i += TPB) {
    const float* src = W + (size_t)i*512 + kbase;
    #pragma unroll
    for (int kk = 0; kk < 16; ++kk) S.wembT[kk*512 + i] = src[kk];
  }
  for (int c = t; c < 256; c += TPB) {
    const float* src = W + (size_t)(512 + c)*512 + kbase;
    #pragma unroll
    for (int kk = 0; kk < 16; ++kk) S.woh[c*16 + kk] = src[kk];
  }
  if (t < 16) {
    S.fc1b[t] = fc1b_g[kbase + t];
    S.fc2b[t] = (t < nrows2) ? fc2b_g[base2 + t] : 0.f;
    S.fc3b[t] = (t < nrows3) ? fc3b_g[base3 + t] : 0.f;
  }
  for (int i = t; i < NV/4; i += TPB) ((int*)S.colors)[i] = 0;
  if (t == 0) {
    S.colors[0] = 1;     // vertex 0: color 0
    S.scali[0] = 1;      // n_used
    S.scalf[0] = 0.f;    // lpp
  }
  // ohdot slice (8 values per block); block 0 also publishes eHval[0]
  {
    #pragma unroll
    for (int rep = 0; rep < 2; ++rep) {
      int c = b*8 + wave*2 + rep;
      const float* wr = W + (size_t)(512 + c)*512;
      float acc = 0.f;
      #pragma unroll
      for (int p = 0; p < 2; ++p) {
        float4 w4 = *(const float4*)&wr[p*256 + lane*4];
        float4 a4 = *(const float4*)&a[EMBD + p*256 + lane*4];
        acc += dot4(w4, a4);
      }
      acc = red64_add(acc);
      if (lane == 0) {
        ohdg[c] = acc;
        if (c == 0) eHvg[0] = acc;   // eH(0) = dot(W_oh[0], a2)
      }
    }
  }
  __syncthreads();
  // HF row 0 = W_oh[0] (this block's slice)
  if (t < 16) HF[kbase + t] = S.woh[0*16 + t];
  // sum-of-squares partials for reg
  {
    float s0=0.f, s1=0.f, s2=0.f, s3=0.f;
    for (int i = t; i < 16*512; i += TPB) {
      float x = S.wembT[i]; s0 += x*x;
      x = S.fc1[i]; s1 += x*x;
      x = S.fc2[i]; s2 += x*x;
    }
    for (int i = t; i < 12*512; i += TPB) { float x = S.fc3[i]; s3 += x*x; }
    for (int i = t; i < 4096; i += TPB)   { float x = S.woh[i]; s0 += x*x; }
    s0 = red64_add(s0); s1 = red64_add(s1); s2 = red64_add(s2); s3 = red64_add(s3);
    if (lane == 0) { S.red[wave*4+0]=s0; S.red[wave*4+1]=s1; S.red[wave*4+2]=s2; S.red[wave*4+3]=s3; }
    __syncthreads();
    if (t == 0) {
      for (int m = 0; m < 4; ++m)
        ssqP[m*GBLK + b] = S.red[m] + S.red[4+m] + S.red[8+m] + S.red[12+m];
    }
  }
  // ---- init barrier (flag-array) ----
  unsigned ep = 1;
  {
    __syncthreads();
    if (t == 0) {
      __threadfence();
      __hip_atomic_store(&flags[b*32], ep, __ATOMIC_RELAXED, __HIP_MEMORY_SCOPE_AGENT);
    }
    if (t < 32) {
      while (__hip_atomic_load(&flags[t*32], __ATOMIC_RELAXED, __HIP_MEMORY_SCOPE_AGENT) < ep) { }
    }
    if (t == 0) __threadfence();
    __syncthreads();
  }
  if (t < 256) S.ohdot[t] = ohdg[t];
  if (b == 0 && t == 0) {
    float reg = 0.f;
    for (int m = 0; m < 4; ++m) {
      float s = 0.f;
      for (int bb = 0; bb < GBLK; ++bb) s += ssqP[m*GBLK + bb];
      reg += sqrtf(s);
    }
    S.scalf[1] = reg;
  }
  __syncthreads();

  // ================= pipelined main loop =================
  // tick: A(va) attn+new_e+fc1+He | B(vb) fc2 | C(vc) fc3 | D(vd) argmax+fold
  int va = 1, vb = 0, vc = 0, vd = 0, d_done = 0;
  ep = 2;

  #pragma unroll 1
  for (;;) {
    const bool canA = (va < NV);

    // ---- staging (prev barrier synced) ----
    if (canA) {
      if (t < 16) {
        int u = adj[va*DEG + t];
        S.nbrs[va & 3][t] = u;
        // attention logit e_j = leaky(eH(u)) for processed, else 0
        float er = 0.f;
        if (u < va) {
          float eh = eHvg[u];
          er = (eh >= 0.f) ? eh : 0.2f * eh;
        }
        S.e[t+1] = er;
        // hazard: any neighbor u<va with u > d_done stalls A
        int ok = (u < va) ? u : 0;
        #pragma unroll
        for (int off = 1; off < 16; off <<= 1) ok = max(ok, __shfl_xor(ok, off, 64));
        if (t == 0) S.runA_sh = (ok <= d_done) ? 1 : 0;
      }
      if (t == 16) S.e[0] = 0.f;
    } else {
      if (t == 0) S.runA_sh = 0;
    }
    if (vb > 0 && t < 128) *(float4*)&S.h1[t*4] = *(const float4*)&h1g[(vb&1)*512 + t*4];
    if (vc > 0) {
      if (t < 100)      *(float4*)&S.h2[t*4] = *(const float4*)&h2g[(vc&1)*512 + t*4];
      else if (t < 128) *(float4*)&S.h2[t*4] = make_float4(0.f,0.f,0.f,0.f);
    }
    if (vd > 0 && t < 80) *(float4*)&S.logits[t*4] = *(const float4*)&logg[(vd&1)*512 + t*4];
    __syncthreads();   // sync0
    const bool runA = (S.runA_sh != 0);

    // prefetch gather rows (independent of attn weights)
    const int c0 = 2*t;
    float2 hv[DEG]; int us[DEG];
    if (runA) {
      #pragma unroll
      for (int j = 0; j < DEG; ++j) {
        int u = S.nbrs[va & 3][j];
        us[j] = u;
        if (u < va) hv[j] = *(const float2*)&HF[(size_t)u*EMBD + c0];
        else        hv[j] = make_float2(0.f, 0.f);
      }
    }

    // ---- phase 1: wave0 = softmax + D ; waves 1-3 = B (fc2) + C (fc3) ----
    if (wave == 0) {
      if (t == 0 && runA) {
        float m = -INFINITY;
        #pragma unroll
        for (int j = 0; j <= DEG; ++j) m = fmaxf(m, S.e[j]);
        float ssum = 0.f;
        float ex[DEG+1];
        #pragma unroll
        for (int j = 0; j <= DEG; ++j) { ex[j] = expf(S.e[j] - m); ssum += ex[j]; }
        #pragma unroll
        for (int j = 0; j <= DEG; ++j) S.attn[j] = ex[j] / ssum;
      }
      if (vd > 0) {
        const int nused = S.scali[0];
        int nc[DEG];
        #pragma unroll
        for (int j = 0; j < DEG; ++j) nc[j] = (int)S.colors[S.nbrs[vd & 3][j]] - 1;
        float sv[5];
        float bm = -INFINITY;
        #pragma unroll
        for (int p = 0; p < 5; ++p) {
          int idx = lane + p*64;
          float val = -INFINITY;
          if (idx < NL) {
            val = S.logits[idx];
            bool msk = (idx >= nused) && (idx < NPCC);
            #pragma unroll
            for (int j = 0; j < DEG; ++j) msk |= (idx == nc[j]);
            if (msk) val = -INFINITY;
          }
          sv[p] = val;
          bm = fmaxf(bm, val);
        }
        #pragma unroll
        for (int off = 1; off < 64; off <<= 1) bm = fmaxf(bm, __shfl_xor(bm, off, 64));
        float ssum = 0.f;
        #pragma unroll
        for (int p = 0; p < 5; ++p) ssum += expf(sv[p] - bm);
        #pragma unroll
        for (int off = 1; off < 64; off <<= 1) ssum += __shfl_xor(ssum, off, 64);
        float bp = -1.f; int bi = NL + 10;
        #pragma unroll
        for (int p = 0; p < 5; ++p) {
          int idx = lane + p*64;
          float pj = (idx < NL) ? (expf(sv[p] - bm) / ssum) : -1.f;
          if (pj > bp) { bp = pj; bi = idx; }
        }
        #pragma unroll
        for (int off = 1; off < 64; off <<= 1) {
          float op = __shfl_xor(bp, off, 64);
          int   oi = __shfl_xor(bi, off, 64);
          if (op > bp || (op == bp && oi < bi)) { bp = op; bi = oi; }
        }
        const int isnew  = (bi == NPCC) ? 1 : 0;
        const int chosen = isnew ? nused : bi;
        if (lane == 0) {
          S.scali[0] = nused + isnew;
          S.scalf[0] += logf(bp + 1e-8f) - logf(1e-8f);
          S.colors[vd] = (unsigned char)(chosen + 1);
        }
        if (lane < 16)
          HF[(size_t)vd*EMBD + kbase + lane] += S.woh[chosen*16 + lane];
        if (b == 0) {
          float pp = (lane < 32) ? eHpg[(vd&3)*32 + lane] : 0.f;
          #pragma unroll
          for (int off = 1; off < 32; off <<= 1) pp += __shfl_xor(pp, off, 64);
          if (lane == 0) eHvg[vd] = pp + S.ohdot[chosen];
        }
      }
    } else {
      // waves 1-3: 24 job slots -> 13 fc2 rows + 9 fc3 rows
      #pragma unroll
      for (int p = 0; p < 2; ++p) {
        int jid = (wave-1)*4 + g + p*12;
        if (jid < 13) {
          if (vb > 0 && jid < nrows2) {
            float acc = 0.f;
            const float* wrow = S.fc2 + jid*512;
            #pragma unroll
            for (int tt = 0; tt < 8; ++tt) {
              float4 x4 = *(const float4*)&S.h1[j16*4 + tt*64];
              float4 w4 = *(const float4*)&wrow[j16*4 + tt*64];
              acc += dot4(x4, w4);
            }
            acc = red16_add(acc);
            if (j16 == 0) {
              float hvv = acc + S.fc2b[jid];
              h2g[(vb&1)*512 + base2 + jid] = (hvv >= 0.f) ? hvv : 0.01f*hvv;
            }
          }
        } else {
          int rr = jid - 13;
          if (vc > 0 && rr < nrows3) {
            float acc = 0.f;
            const float* wrow = S.fc3 + rr*512;
            #pragma unroll
            for (int tt = 0; tt < 8; ++tt) {
              float4 x4 = *(const float4*)&S.h2[j16*4 + tt*64];
              float4 w4 = *(const float4*)&wrow[j16*4 + tt*64];
              acc += dot4(x4, w4);
            }
            acc = red16_add(acc);
            if (j16 == 0) logg[(vc&1)*512 + base3 + rr] = acc + S.fc3b[rr];
          }
        }
      }
    }
    __syncthreads();   // sync1 (attn ready)

    // ---- phase 2: weighted aggregate + ELU -> new_e ----
    if (runA) {
      float acc0 = 0.f, acc1 = 0.f;
      #pragma unroll
      for (int j = 0; j < DEG; ++j) {
        if (us[j] < va) {
          float ax = S.attn[j+1];
          acc0 += ax * hv[j].x;
          acc1 += ax * hv[j].y;
        }
      }
      S.newe[c0]   = (acc0 > 0.f) ? acc0 : expm1f(acc0);
      S.newe[c0+1] = (acc1 > 0.f) ? acc1 : expm1f(acc1);
    }
    __syncthreads();   // sync2

    // ---- phase 3: fc1 slice + He(va) slice ----
    if (runA) {
      const int r = wave*4 + g;
      float acc = 0.f;
      const float* wrow = S.fc1 + r*512;
      #pragma unroll
      for (int tt = 0; tt < 8; ++tt) {
        float4 x4 = *(const float4*)&S.newe[j16*4 + tt*64];
        float4 w4 = *(const float4*)&wrow[j16*4 + tt*64];
        acc += dot4(x4, w4);
      }
      acc = red16_add(acc);
      if (j16 == 0) {
        float hvv = acc + S.fc1b[r];
        h1g[(va&1)*512 + kbase + r] = (hvv >= 0.f) ? hvv : 0.01f*hvv;
      }
      float acc2 = 0.f;
      const float* w2row = S.wembT + r*512;
      #pragma unroll
      for (int tt = 0; tt < 8; ++tt) {
        float4 x4 = *(const float4*)&S.newe[j16*4 + tt*64];
        float4 w4 = *(const float4*)&w2row[j16*4 + tt*64];
        acc2 += dot4(x4, w4);
      }
      acc2 = red16_add(acc2);
      if (j16 == 0) {
        HF[(size_t)va*EMBD + kbase + r] = acc2;
        S.hev[r] = acc2;
      }
    }

    // ---- barrier (with embedded eH partial publish) ----
    __syncthreads();
    if (runA && t == 0) {
      float pp = 0.f;
      #pragma unroll
      for (int kk = 0; kk < 16; ++kk) pp += S.hev[kk] * S.a2[kbase + kk];
      eHpg[(va&3)*32 + b] = pp;
    }
    if (t == 0) {
      __threadfence();
      __hip_atomic_store(&flags[b*32], ep, __ATOMIC_RELAXED, __HIP_MEMORY_SCOPE_AGENT);
    }
    if (t < 32) {
      while (__hip_atomic_load(&flags[t*32], __ATOMIC_RELAXED, __HIP_MEMORY_SCOPE_AGENT) < ep) { }
    }
    if (t == 0) __threadfence();
    __syncthreads();

    // ---- advance pipeline ----
    if (vd > 0) d_done = vd;
    vd = vc;
    vc = vb;
    vb = runA ? va : 0;
    va += runA ? 1 : 0;
    ++ep;
    if (d_done == NV-1) break;
  }

  // ================= output =================
  if (b == 0) {
    for (int i = t; i < NV; i += TPB) out[i] = (float)((int)S.colors[i] - 1);
    if (t == 0) {
      int bv = basep[0];
      int bl = (bv >= -100000 && bv <= 100000) ? bv : (int)__int_as_float(bv);
      float loss = ((float)(S.scali[0] - bl)) * S.scalf[0] / 8192.0f + 0.05f * S.scalf[1];
      out[NV] = loss;
    }
  }
}

extern "C" void kernel_launch(void* const* d_in, const int* in_sizes, int n_in,
                              void* d_out, int out_size, void* d_ws, size_t ws_size,
                              hipStream_t stream) {
  const int*   adj  = (const int*)d_in[0];
  const float* W    = (const float*)d_in[1];
  const float* av   = (const float*)d_in[2];
  const float* f1w  = (const float*)d_in[3];
  const float* f1b  = (const float*)d_in[4];
  const float* f2w  = (const float*)d_in[5];
  const float* f2b  = (const float*)d_in[6];
  const float* f3w  = (const float*)d_in[7];
  const float* f3b  = (const float*)d_in[8];
  const int*   bas  = (const int*)d_in[9];
  float* out = (float*)d_out;
  unsigned char* ws = (unsigned char*)d_ws;

  // zero barrier flags (workspace is poisoned 0xAA before every launch)
  (void)hipMemsetAsync(d_ws, 0, 8192, stream);
  (void)hipFuncSetAttribute((const void*)gc_kernel,
                      hipFuncAttributeMaxDynamicSharedMemorySize,
                      (int)sizeof(Smem));
  gc_kernel<<<dim3(GBLK), dim3(TPB), sizeof(Smem), stream>>>(
      adj, W, av, f1w, f1b, f2w, f2b, f3w, f3b, bas, out, ws);
}

// Round 4
// 59536.072 us; speedup vs baseline: 2.0008x; 1.3657x over previous
//
#include <hip/hip_runtime.h>
#include <math.h>

#define NV    8192
#define DEG   16
#define EMBD  512
#define NPCC  256
#define NL    257
#define GBLK  32
#define TPB   256
#define K     8

// workspace layout (bytes)
#define WS_FLAG  0        // 32 flags, 128B apart (4 KB)
#define WS_SSQ   4096     // 4*32 floats
#define WS_OHD   5120     // 256 floats
#define WS_H1    8192     // ring2 x 8 x 512 floats (32 KB)
#define WS_H2    40960    // ring2 x 8 x 512 floats (32 KB)
#define WS_LOG   73728    // ring2 x 8 x 260 floats (16.6 KB)
#define WS_EHP   90368    // ring32 x 32 floats (4 KB)
#define WS_EHV   98304    // 8192 floats (32 KB)
#define WS_HF    131072   // 8192*512 floats = 16 MB

struct __align__(16) Smem {
  float wembT[16*512];   // W[:, kslice] transposed: [out][in]
  float fc1[16*512];
  float fc2[13*512];     // padded rows zero
  float fc3[9*512];      // padded rows/cols zero
  float woh[256*16];     // W_oh[:, kslice]
  float ohdot[256];
  float a2[512];
  float newe[512];
  float logits[8*260];   // staged D-batch logits
  float e[8][20];
  float attn[8][20];
  float hev[8][16];
  float fc1b[16];
  float fc2b[16];
  float fc3b[16];
  float red[16];
  float scalf[4];        // 0: lpp, 1: reg
  int   scali[4];        // 0: n_used
  int   nbrs[4][8][16];  // ring by tick&3
  int   bmeta[4][2];     // ring: v0, n
  int   chosen[8];
  int   slotbad[8];
  unsigned char colors[NV];
};
static_assert(sizeof(Smem) <= 160*1024, "LDS overflow");

__device__ __forceinline__ float dot4(const float4 a, const float4 b) {
  return a.x*b.x + a.y*b.y + a.z*b.z + a.w*b.w;
}
__device__ __forceinline__ float red64_add(float x) {
  #pragma unroll
  for (int off = 1; off < 64; off <<= 1) x += __shfl_xor(x, off, 64);
  return x;
}
__device__ __forceinline__ float red16_add(float x) {
  #pragma unroll
  for (int off = 1; off < 16; off <<= 1) x += __shfl_xor(x, off, 64);
  return x;
}

#define GATHER(SS, HV) do {                                                  \
  int _vv = va + (SS);                                                       \
  _Pragma("unroll")                                                          \
  for (int _j = 0; _j < 16; ++_j) {                                          \
    int _u = S.nbrs[tk3][SS][_j];                                            \
    if (_u < _vv) HV[_j] = *(const float2*)&HF[(size_t)_u*EMBD + c0];        \
    else          HV[_j] = make_float2(0.f, 0.f);                            \
  }                                                                          \
} while (0)

#define SLOT_A(SS, HV) do {                                                  \
  float _a0 = 0.f, _a1 = 0.f;                                                \
  _Pragma("unroll")                                                          \
  for (int _j = 0; _j < 16; ++_j) {                                          \
    float _ax = S.attn[SS][_j+1];                                            \
    _a0 += _ax * HV[_j].x; _a1 += _ax * HV[_j].y;                            \
  }                                                                          \
  if ((SS) + 2 < n) { GATHER((SS)+2, HV); }                                  \
  S.newe[c0]   = (_a0 > 0.f) ? _a0 : expm1f(_a0);                            \
  S.newe[c0+1] = (_a1 > 0.f) ? _a1 : expm1f(_a1);                            \
  __syncthreads();                                                           \
  { int _r = wave*4 + g;                                                     \
    float _acc = 0.f; const float* _wr = S.fc1 + _r*512;                     \
    _Pragma("unroll")                                                        \
    for (int _tt = 0; _tt < 8; ++_tt) {                                      \
      float4 _x = *(const float4*)&S.newe[j16*4 + _tt*64];                   \
      float4 _w = *(const float4*)&_wr[j16*4 + _tt*64];                      \
      _acc += dot4(_x, _w);                                                  \
    }                                                                        \
    _acc = red16_add(_acc);                                                  \
    if (j16 == 0) {                                                          \
      float _h = _acc + S.fc1b[_r];                                          \
      h1g[(T&1)*4096 + (SS)*512 + kbase + _r] = (_h >= 0.f) ? _h : 0.01f*_h; \
    }                                                                        \
    float _ac2 = 0.f; const float* _w2 = S.wembT + _r*512;                   \
    _Pragma("unroll")                                                        \
    for (int _tt = 0; _tt < 8; ++_tt) {                                      \
      float4 _x = *(const float4*)&S.newe[j16*4 + _tt*64];                   \
      float4 _w = *(const float4*)&_w2[j16*4 + _tt*64];                      \
      _ac2 += dot4(_x, _w);                                                  \
    }                                                                        \
    _ac2 = red16_add(_ac2);                                                  \
    if (j16 == 0) {                                                          \
      HF[(size_t)(va+(SS))*EMBD + kbase + _r] = _ac2;                        \
      S.hev[SS][_r] = _ac2;                                                  \
    }                                                                        \
  }                                                                          \
  __syncthreads();                                                           \
} while (0)

__global__ void __launch_bounds__(TPB, 1)
gc_kernel(const int* __restrict__ adj, const float* __restrict__ W,
          const float* __restrict__ a, const float* __restrict__ fc1w,
          const float* __restrict__ fc1b_g, const float* __restrict__ fc2w,
          const float* __restrict__ fc2b_g, const float* __restrict__ fc3w,
          const float* __restrict__ fc3b_g, const int* __restrict__ basep,
          float* __restrict__ out, unsigned char* __restrict__ ws)
{
  extern __shared__ char smem_raw[];
  Smem& S = *reinterpret_cast<Smem*>(smem_raw);
  const int b    = blockIdx.x;
  const int t    = threadIdx.x;
  const int wave = t >> 6;
  const int lane = t & 63;
  const int g    = lane >> 4;
  const int j16  = lane & 15;

  unsigned* flags = (unsigned*)(ws + WS_FLAG);
  float* ssqP  = (float*)(ws + WS_SSQ);
  float* ohdg  = (float*)(ws + WS_OHD);
  float* h1g   = (float*)(ws + WS_H1);
  float* h2g   = (float*)(ws + WS_H2);
  float* logg  = (float*)(ws + WS_LOG);
  float* eHpg  = (float*)(ws + WS_EHP);
  float* eHvg  = (float*)(ws + WS_EHV);
  float* HF    = (float*)(ws + WS_HF);

  const int kbase  = b * 16;
  const int nrows2 = (b < 16) ? 13 : 12;
  const int base2  = (b < 16) ? 13*b : 208 + 12*(b-16);
  const int nrows3 = (b == 0) ? 9 : 8;
  const int base3  = (b == 0) ? 0 : 8*b + 1;

  // ================= init =================
  for (int i = t; i < EMBD; i += TPB) S.a2[i] = a[EMBD + i];
  for (int i = t; i < 16*512; i += TPB) S.fc1[i] = fc1w[(size_t)kbase*512 + i];
  for (int i = t; i < 13*512; i += TPB) {
    int rr = i >> 9;
    S.fc2[i] = (rr < nrows2) ? fc2w[(size_t)base2*512 + i] : 0.f;
  }
  for (int i = t; i < 9*512; i += TPB) {
    int rr = i >> 9, cc = i & 511;
    S.fc3[i] = (rr < nrows3 && cc < 400) ? fc3w[(size_t)(base3+rr)*400 + cc] : 0.f;
  }
  for (int i = t; i < 512; i += TPB) {
    const float* src = W + (size_t)i*512 + kbase;
    #pragma unroll
    for (int kk = 0; kk < 16; ++kk) S.wembT[kk*512 + i] = src[kk];
  }
  for (int c = t; c < 256; c += TPB) {
    const float* src = W + (size_t)(512 + c)*512 + kbase;
    #pragma unroll
    for (int kk = 0; kk < 16; ++kk) S.woh[c*16 + kk] = src[kk];
  }
  if (t < 16) {
    S.fc1b[t] = fc1b_g[kbase + t];
    S.fc2b[t] = (t < nrows2) ? fc2b_g[base2 + t] : 0.f;
    S.fc3b[t] = (t < nrows3) ? fc3b_g[base3 + t] : 0.f;
  }
  for (int i = t; i < NV/4; i += TPB) ((int*)S.colors)[i] = 0;
  if (t < 8) ((int*)S.bmeta)[t] = 0;
  if (t == 0) {
    S.colors[0] = 1;     // vertex 0: color 0
    S.scali[0] = 1;      // n_used
    S.scalf[0] = 0.f;    // lpp
  }
  // ohdot slice (8 values per block); block 0 also publishes eHval[0]
  {
    #pragma unroll
    for (int rep = 0; rep < 2; ++rep) {
      int c = b*8 + wave*2 + rep;
      const float* wr = W + (size_t)(512 + c)*512;
      float acc = 0.f;
      #pragma unroll
      for (int p = 0; p < 2; ++p) {
        float4 w4 = *(const float4*)&wr[p*256 + lane*4];
        float4 a4 = *(const float4*)&a[EMBD + p*256 + lane*4];
        acc += dot4(w4, a4);
      }
      acc = red64_add(acc);
      if (lane == 0) {
        ohdg[c] = acc;
        if (c == 0) eHvg[0] = acc;   // eH(0) = dot(W_oh[0], a2)
      }
    }
  }
  __syncthreads();
  // HF row 0 = W_oh[0] (this block's slice)
  if (t < 16) HF[kbase + t] = S.woh[t];
  // sum-of-squares partials for reg
  {
    float s0=0.f, s1=0.f, s2=0.f, s3=0.f;
    for (int i = t; i < 16*512; i += TPB) {
      float x = S.wembT[i]; s0 += x*x;
      x = S.fc1[i]; s1 += x*x;
    }
    for (int i = t; i < 13*512; i += TPB) { float x = S.fc2[i]; s2 += x*x; }
    for (int i = t; i < 9*512; i += TPB)  { float x = S.fc3[i]; s3 += x*x; }
    for (int i = t; i < 4096; i += TPB)   { float x = S.woh[i]; s0 += x*x; }
    s0 = red64_add(s0); s1 = red64_add(s1); s2 = red64_add(s2); s3 = red64_add(s3);
    if (lane == 0) { S.red[wave*4+0]=s0; S.red[wave*4+1]=s1; S.red[wave*4+2]=s2; S.red[wave*4+3]=s3; }
    __syncthreads();
    if (t == 0) {
      for (int m = 0; m < 4; ++m)
        ssqP[m*GBLK + b] = S.red[m] + S.red[4+m] + S.red[8+m] + S.red[12+m];
    }
  }
  // ---- init barrier (release store + relaxed spin + acquire) ----
  unsigned ep = 1;
  __syncthreads();
  if (t == 0) __hip_atomic_store(&flags[b*32], ep, __ATOMIC_RELEASE, __HIP_MEMORY_SCOPE_AGENT);
  if (t < 32) {
    while (__hip_atomic_load(&flags[t*32], __ATOMIC_RELAXED, __HIP_MEMORY_SCOPE_AGENT) < ep) { }
  }
  if (t == 0) (void)__hip_atomic_load(&flags[0], __ATOMIC_ACQUIRE, __HIP_MEMORY_SCOPE_AGENT);
  __syncthreads();

  if (t < 256) S.ohdot[t] = ohdg[t];
  if (b == 0 && t == 0) {
    float reg = 0.f;
    for (int m = 0; m < 4; ++m) {
      float s = 0.f;
      for (int bb = 0; bb < GBLK; ++bb) s += ssqP[m*GBLK + bb];
      reg += sqrtf(s);
    }
    S.scalf[1] = reg;
  }
  __syncthreads();

  // ================= batched pipelined main loop =================
  int va = 1, d_done = 0;
  unsigned T = 0;

  #pragma unroll 1
  for (;;) {
    const int tk3  = (int)(T & 3);
    const int idxD = (int)((T+1) & 3);
    const int idxC = (int)((T+2) & 3);
    const int idxB = (int)((T+3) & 3);
    const int v0D = S.bmeta[idxD][0], nD = S.bmeta[idxD][1];
    const int nC  = S.bmeta[idxC][1];
    const int nB  = S.bmeta[idxB][1];
    const bool canA = (va < NV);
    const int Kc = canA ? ((NV - va < K) ? (NV - va) : K) : 0;

    // ---- phase 0: candidate batch staging + safety + D logits staging ----
    if (t < Kc*DEG) {
      int s = t >> 4, j = t & 15;
      int v = va + s;
      int u = adj[v*DEG + j];
      S.nbrs[tk3][s][j] = u;
      bool bad = false;
      float er = 0.f;
      if (u < v) {
        if (u > d_done) bad = true;
        else { float eh = eHvg[u]; er = (eh >= 0.f) ? eh : 0.2f*eh; }
      }
      S.e[s][j+1] = er;
      unsigned long long bm = __ballot(bad);
      if (j == 0) S.slotbad[s] = (int)((bm >> (((t >> 4) & 3)*16)) & 0xFFFFull);
    }
    if (t < K) S.e[t][0] = 0.f;
    for (int x = t; x < nD*260; x += TPB)
      S.logits[x] = logg[((T+1)&1)*2080 + x];
    __syncthreads();   // sync0

    int n = 0;
    while (n < Kc && S.slotbad[n] == 0) ++n;
    if (t == 0) { S.bmeta[tk3][0] = va; S.bmeta[tk3][1] = n; }

    const int c0 = 2*t;
    float2 hv0[16], hv1[16];
    if (n > 0) GATHER(0, hv0);
    if (n > 1) GATHER(1, hv1);

    // ---- phase 1: wave0 = attn-softmax + D ; waves1-3 = B (fc2) + C (fc3) ----
    if (wave == 0) {
      if (lane < n) {
        float m = 0.f;   // includes e[0]=0
        #pragma unroll
        for (int j = 1; j <= DEG; ++j) m = fmaxf(m, S.e[lane][j]);
        float ex[DEG+1]; float ssum = 0.f;
        #pragma unroll
        for (int j = 0; j <= DEG; ++j) { ex[j] = expf(S.e[lane][j] - m); ssum += ex[j]; }
        #pragma unroll
        for (int j = 0; j <= DEG; ++j) S.attn[lane][j] = ex[j] / ssum;
      }
      if (nD > 0) {
        int nused = S.scali[0];
        float lpp = S.scalf[0];
        // prefetch fold-olds and eH partials
        float oldA = 0.f, oldB2 = 0.f;
        {
          int sp0 = g, sp1 = 4 + g;
          if (sp0 < nD) oldA  = HF[(size_t)(v0D+sp0)*EMBD + kbase + j16];
          if (sp1 < nD) oldB2 = HF[(size_t)(v0D+sp1)*EMBD + kbase + j16];
        }
        float ppre[8] = {0,0,0,0,0,0,0,0};
        if (b == 0 && lane < 32) {
          #pragma unroll
          for (int s2 = 0; s2 < 8; ++s2)
            if (s2 < nD) ppre[s2] = eHpg[((v0D+s2)&31)*32 + lane];
        }
        #pragma unroll
        for (int s2 = 0; s2 < 8; ++s2) {
          if (s2 >= nD) break;
          const int vD = v0D + s2;
          int nc[DEG];
          #pragma unroll
          for (int j = 0; j < DEG; ++j) nc[j] = (int)S.colors[S.nbrs[idxD][s2][j]] - 1;
          float sv[5]; float bmx = -INFINITY;
          #pragma unroll
          for (int p = 0; p < 5; ++p) {
            int idx = lane + p*64;
            float val = -INFINITY;
            if (idx < NL) {
              val = S.logits[s2*260 + idx];
              bool msk = (idx >= nused) && (idx < NPCC);
              #pragma unroll
              for (int j = 0; j < DEG; ++j) msk |= (idx == nc[j]);
              if (msk) val = -INFINITY;
            }
            sv[p] = val;
            bmx = fmaxf(bmx, val);
          }
          #pragma unroll
          for (int off = 1; off < 64; off <<= 1) bmx = fmaxf(bmx, __shfl_xor(bmx, off, 64));
          float ssum = 0.f;
          #pragma unroll
          for (int p = 0; p < 5; ++p) ssum += expf(sv[p] - bmx);
          #pragma unroll
          for (int off = 1; off < 64; off <<= 1) ssum += __shfl_xor(ssum, off, 64);
          float bp = -1.f; int bi = NL + 10;
          #pragma unroll
          for (int p = 0; p < 5; ++p) {
            int idx = lane + p*64;
            float pj = (idx < NL) ? (expf(sv[p] - bmx) / ssum) : -1.f;
            if (pj > bp) { bp = pj; bi = idx; }
          }
          #pragma unroll
          for (int off = 1; off < 64; off <<= 1) {
            float op = __shfl_xor(bp, off, 64);
            int   oi = __shfl_xor(bi, off, 64);
            if (op > bp || (op == bp && oi < bi)) { bp = op; bi = oi; }
          }
          const int isnew  = (bi == NPCC) ? 1 : 0;
          const int chosen = isnew ? nused : bi;
          nused += isnew;
          lpp += logf(bp + 1e-8f) - logf(1e-8f);
          if (lane == 0) {
            S.colors[vD] = (unsigned char)(chosen + 1);
            S.chosen[s2] = chosen;
          }
          if (b == 0) {
            float pp = (lane < 32) ? ppre[s2] : 0.f;
            #pragma unroll
            for (int off = 1; off < 32; off <<= 1) pp += __shfl_xor(pp, off, 64);
            if (lane == 0) eHvg[vD] = pp + S.ohdot[chosen];
          }
        }
        if (lane == 0) { S.scali[0] = nused; S.scalf[0] = lpp; }
        // W_oh folds (parallel, 2 passes)
        {
          int sp0 = g, sp1 = 4 + g;
          if (sp0 < nD)
            HF[(size_t)(v0D+sp0)*EMBD + kbase + j16] = oldA  + S.woh[S.chosen[sp0]*16 + j16];
          if (sp1 < nD)
            HF[(size_t)(v0D+sp1)*EMBD + kbase + j16] = oldB2 + S.woh[S.chosen[sp1]*16 + j16];
        }
      }
    } else {
      // waves 1-3: B jobs (nB*13) then C jobs (nC*9) on 12 groups
      const int grp  = (wave-1)*4 + g;
      const int totB = nB*13;
      const int tot  = totB + nC*9;
      for (int jid = grp; jid < tot; jid += 12) {
        if (jid < totB) {
          int s2 = jid/13, r = jid - s2*13;
          if (r < nrows2) {
            const float* xp = h1g + ((T+1)&1)*4096 + s2*512;
            float acc = 0.f; const float* wrow = S.fc2 + r*512;
            #pragma unroll
            for (int tt = 0; tt < 8; ++tt) {
              float4 x4 = *(const float4*)&xp[j16*4 + tt*64];
              float4 w4 = *(const float4*)&wrow[j16*4 + tt*64];
              acc += dot4(x4, w4);
            }
            acc = red16_add(acc);
            if (j16 == 0) {
              float hvv = acc + S.fc2b[r];
              h2g[(T&1)*4096 + s2*512 + base2 + r] = (hvv >= 0.f) ? hvv : 0.01f*hvv;
            }
          }
        } else {
          int jj = jid - totB; int s2 = jj/9, r = jj - s2*9;
          if (r < nrows3) {
            const float* xp = h2g + ((T+1)&1)*4096 + s2*512;
            float acc = 0.f; const float* wrow = S.fc3 + r*512;
            #pragma unroll
            for (int tt = 0; tt < 8; ++tt) {
              float4 x4 = *(const float4*)&xp[j16*4 + tt*64];
              float4 w4 = *(const float4*)&wrow[j16*4 + tt*64];
              acc += dot4(x4, w4);
            }
            acc = red16_add(acc);
            if (j16 == 0) logg[(T&1)*2080 + s2*260 + base3 + r] = acc + S.fc3b[r];
          }
        }
      }
    }
    __syncthreads();   // sync1

    // ---- phase 2: A-stage slot loop (weighted agg + ELU + fc1 + He) ----
    for (int s = 0; s < K; s += 2) {
      if (s >= n) break;
      SLOT_A(s, hv0);
      if (s+1 < n) { SLOT_A(s+1, hv1); }
    }

    // ---- phase 3: eH partials + global barrier ----
    if (t < n) {
      float pp = 0.f;
      #pragma unroll
      for (int kk = 0; kk < 16; ++kk) pp += S.hev[t][kk] * S.a2[kbase + kk];
      eHpg[((va+t)&31)*32 + b] = pp;
    }
    __syncthreads();
    ++ep;
    if (t == 0) __hip_atomic_store(&flags[b*32], ep, __ATOMIC_RELEASE, __HIP_MEMORY_SCOPE_AGENT);
    if (t < 32) {
      while (__hip_atomic_load(&flags[t*32], __ATOMIC_RELAXED, __HIP_MEMORY_SCOPE_AGENT) < ep) { }
    }
    if (t == 0) (void)__hip_atomic_load(&flags[0], __ATOMIC_ACQUIRE, __HIP_MEMORY_SCOPE_AGENT);
    __syncthreads();

    // ---- advance ----
    if (nD > 0) d_done = v0D + nD - 1;
    va += n;
    ++T;
    if (d_done == NV-1) break;
    if (T > 12000u) break;   // safety: fail validation instead of hanging
  }

  // ================= output =================
  if (b == 0) {
    for (int i = t; i < NV; i += TPB) out[i] = (float)((int)S.colors[i] - 1);
    if (t == 0) {
      int bv = basep[0];
      int bl = (bv >= -100000 && bv <= 100000) ? bv : (int)__int_as_float(bv);
      float loss = ((float)(S.scali[0] - bl)) * S.scalf[0] / 8192.0f + 0.05f * S.scalf[1];
      out[NV] = loss;
    }
  }
}

extern "C" void kernel_launch(void* const* d_in, const int* in_sizes, int n_in,
                              void* d_out, int out_size, void* d_ws, size_t ws_size,
                              hipStream_t stream) {
  const int*   adj  = (const int*)d_in[0];
  const float* W    = (const float*)d_in[1];
  const float* av   = (const float*)d_in[2];
  const float* f1w  = (const float*)d_in[3];
  const float* f1b  = (const float*)d_in[4];
  const float* f2w  = (const float*)d_in[5];
  const float* f2b  = (const float*)d_in[6];
  const float* f3w  = (const float*)d_in[7];
  const float* f3b  = (const float*)d_in[8];
  const int*   bas  = (const int*)d_in[9];
  float* out = (float*)d_out;
  unsigned char* ws = (unsigned char*)d_ws;

  // zero barrier flags (workspace is poisoned 0xAA before every launch)
  (void)hipMemsetAsync(d_ws, 0, 8192, stream);
  (void)hipFuncSetAttribute((const void*)gc_kernel,
                      hipFuncAttributeMaxDynamicSharedMemorySize,
                      (int)sizeof(Smem));
  gc_kernel<<<dim3(GBLK), dim3(TPB), sizeof(Smem), stream>>>(
      adj, W, av, f1w, f1b, f2w, f2b, f3w, f3b, bas, out, ws);
}

// Round 5
// 48716.110 us; speedup vs baseline: 2.4452x; 1.2221x over previous
//
#include <hip/hip_runtime.h>
#include <math.h>

#define NV    8192
#define DEG   16
#define EMBD  512
#define NPCC  256
#define NL    257
#define GBLK  32
#define TPB   256
#define K     10

// workspace layout (bytes)
#define WS_FLAG  0        // 32 flags, 128B apart (4 KB)
#define WS_SSQ   4096     // 4*32 floats
#define WS_OHD   5120     // 256 floats
#define WS_H1    8192     // ring2 x K x 512 floats (40960 B)
#define WS_H2    49152    // ring2 x K x 512 floats (40960 B)
#define WS_LOG   90112    // ring2 x K x 260 floats (20800 B)
#define WS_EHP   110912   // ring64 x 32 floats (8192 B)
#define WS_EHV   119104   // 8192 floats (32768 B)
#define WS_HF    152064   // 8192*512 floats = 16 MB

struct __align__(16) Smem {
  float wembT[16*512];   // W[:, kslice] transposed: [out][in]
  float fc1[16*512];
  float fc2[13*512];     // padded rows zero
  float fc3[9*512];      // padded rows/cols zero
  float ohdot[256];
  float a2[512];
  float newe8[K][512];
  float logits[K*260];   // staged D-batch logits
  float e[K][20];
  float attn[K][20];
  float hev[K][16];
  float fc1b[16];
  float fc2b[16];
  float fc3b[16];
  float red[16];
  float scalf[4];        // 0: lpp, 1: reg
  int   scali[4];        // 0: n_used
  int   nbrs[4][K][16];  // ring by tick&3
  int   bmeta[4][2];     // ring: v0, n
  int   chosen[K];
  int   slotbad[K];
  unsigned char colors[NV];
};
static_assert(sizeof(Smem) <= 160*1024, "LDS overflow");

__device__ __forceinline__ float dot4(const float4 a, const float4 b) {
  return a.x*b.x + a.y*b.y + a.z*b.z + a.w*b.w;
}
__device__ __forceinline__ float red64_add(float x) {
  #pragma unroll
  for (int off = 1; off < 64; off <<= 1) x += __shfl_xor(x, off, 64);
  return x;
}
__device__ __forceinline__ float red16_add(float x) {
  #pragma unroll
  for (int off = 1; off < 16; off <<= 1) x += __shfl_xor(x, off, 64);
  return x;
}

#define GATHER(SS, HV) do {                                                  \
  int _vv = va + (SS);                                                       \
  _Pragma("unroll")                                                          \
  for (int _j = 0; _j < 16; ++_j) {                                          \
    int _u = S.nbrs[tk3][SS][_j];                                            \
    if (_u < _vv) HV[_j] = *(const float2*)&HF[(size_t)_u*EMBD + c0];        \
    else          HV[_j] = make_float2(0.f, 0.f);                            \
  }                                                                          \
} while (0)

#define AGG(SS, HV) do {                                                     \
  float _a0 = 0.f, _a1 = 0.f;                                                \
  _Pragma("unroll")                                                          \
  for (int _j = 0; _j < 16; ++_j) {                                          \
    float _ax = S.attn[SS][_j+1];                                            \
    _a0 += _ax * HV[_j].x; _a1 += _ax * HV[_j].y;                            \
  }                                                                          \
  S.newe8[SS][c0]   = (_a0 > 0.f) ? _a0 : expm1f(_a0);                       \
  S.newe8[SS][c0+1] = (_a1 > 0.f) ? _a1 : expm1f(_a1);                       \
} while (0)

__global__ void __launch_bounds__(TPB, 1)
gc_kernel(const int* __restrict__ adj, const float* __restrict__ W,
          const float* __restrict__ a, const float* __restrict__ fc1w,
          const float* __restrict__ fc1b_g, const float* __restrict__ fc2w,
          const float* __restrict__ fc2b_g, const float* __restrict__ fc3w,
          const float* __restrict__ fc3b_g, const int* __restrict__ basep,
          float* __restrict__ out, unsigned char* __restrict__ ws)
{
  extern __shared__ char smem_raw[];
  Smem& S = *reinterpret_cast<Smem*>(smem_raw);
  const int b    = blockIdx.x;
  const int t    = threadIdx.x;
  const int wave = t >> 6;
  const int lane = t & 63;
  const int g    = lane >> 4;
  const int j16  = lane & 15;

  unsigned* flags = (unsigned*)(ws + WS_FLAG);
  float* ssqP  = (float*)(ws + WS_SSQ);
  float* ohdg  = (float*)(ws + WS_OHD);
  float* h1g   = (float*)(ws + WS_H1);
  float* h2g   = (float*)(ws + WS_H2);
  float* logg  = (float*)(ws + WS_LOG);
  float* eHpg  = (float*)(ws + WS_EHP);
  float* eHvg  = (float*)(ws + WS_EHV);
  float* HF    = (float*)(ws + WS_HF);

  const int kbase  = b * 16;
  const int nrows2 = (b < 16) ? 13 : 12;
  const int base2  = (b < 16) ? 13*b : 208 + 12*(b-16);
  const int nrows3 = (b == 0) ? 9 : 8;
  const int base3  = (b == 0) ? 0 : 8*b + 1;

  // ================= init =================
  for (int i = t; i < EMBD; i += TPB) S.a2[i] = a[EMBD + i];
  for (int i = t; i < 16*512; i += TPB) S.fc1[i] = fc1w[(size_t)kbase*512 + i];
  for (int i = t; i < 13*512; i += TPB) {
    int rr = i >> 9;
    S.fc2[i] = (rr < nrows2) ? fc2w[(size_t)base2*512 + i] : 0.f;
  }
  for (int i = t; i < 9*512; i += TPB) {
    int rr = i >> 9, cc = i & 511;
    S.fc3[i] = (rr < nrows3 && cc < 400) ? fc3w[(size_t)(base3+rr)*400 + cc] : 0.f;
  }
  for (int i = t; i < 512; i += TPB) {
    const float* src = W + (size_t)i*512 + kbase;
    #pragma unroll
    for (int kk = 0; kk < 16; ++kk) S.wembT[kk*512 + i] = src[kk];
  }
  if (t < 16) {
    S.fc1b[t] = fc1b_g[kbase + t];
    S.fc2b[t] = (t < nrows2) ? fc2b_g[base2 + t] : 0.f;
    S.fc3b[t] = (t < nrows3) ? fc3b_g[base3 + t] : 0.f;
  }
  for (int i = t; i < NV/4; i += TPB) ((int*)S.colors)[i] = 0;
  if (t < 8) ((int*)S.bmeta)[t] = 0;
  if (t == 0) {
    S.colors[0] = 1;     // vertex 0: color 0
    S.scali[0] = 1;      // n_used
    S.scalf[0] = 0.f;    // lpp
  }
  // ohdot slice (8 values per block); block 0 also publishes eHval[0]
  {
    #pragma unroll
    for (int rep = 0; rep < 2; ++rep) {
      int c = b*8 + wave*2 + rep;
      const float* wr = W + (size_t)(512 + c)*512;
      float acc = 0.f;
      #pragma unroll
      for (int p = 0; p < 2; ++p) {
        float4 w4 = *(const float4*)&wr[p*256 + lane*4];
        float4 a4 = *(const float4*)&a[EMBD + p*256 + lane*4];
        acc += dot4(w4, a4);
      }
      acc = red64_add(acc);
      if (lane == 0) {
        ohdg[c] = acc;
        if (c == 0) eHvg[0] = acc;   // eH(0) = dot(W_oh[0], a2)
      }
    }
  }
  __syncthreads();
  // HF row 0 = W_oh[0] (this block's slice) straight from global W
  if (t < 16) HF[kbase + t] = W[(size_t)512*512 + kbase + t];
  // sum-of-squares partials for reg
  {
    float s0=0.f, s1=0.f, s2=0.f, s3=0.f;
    for (int i = t; i < 16*512; i += TPB) {
      float x = S.wembT[i]; s0 += x*x;
      x = S.fc1[i]; s1 += x*x;
    }
    for (int i = t; i < 13*512; i += TPB) { float x = S.fc2[i]; s2 += x*x; }
    for (int i = t; i < 9*512; i += TPB)  { float x = S.fc3[i]; s3 += x*x; }
    for (int i = t; i < 4096; i += TPB) {   // W_oh slice from global
      int c = i >> 4, kk = i & 15;
      float x = W[(size_t)(512 + c)*512 + kbase + kk];
      s0 += x*x;
    }
    s0 = red64_add(s0); s1 = red64_add(s1); s2 = red64_add(s2); s3 = red64_add(s3);
    if (lane == 0) { S.red[wave*4+0]=s0; S.red[wave*4+1]=s1; S.red[wave*4+2]=s2; S.red[wave*4+3]=s3; }
    __syncthreads();
    if (t == 0) {
      for (int m = 0; m < 4; ++m)
        ssqP[m*GBLK + b] = S.red[m] + S.red[4+m] + S.red[8+m] + S.red[12+m];
    }
  }
  // ---- init barrier ----
  unsigned ep = 1;
  __syncthreads();
  if (t == 0) __hip_atomic_store(&flags[b*32], ep, __ATOMIC_RELEASE, __HIP_MEMORY_SCOPE_AGENT);
  if (t < 32) {
    while (__hip_atomic_load(&flags[t*32], __ATOMIC_RELAXED, __HIP_MEMORY_SCOPE_AGENT) < ep) { }
  }
  if (t == 0) (void)__hip_atomic_load(&flags[0], __ATOMIC_ACQUIRE, __HIP_MEMORY_SCOPE_AGENT);
  __syncthreads();

  if (t < 256) S.ohdot[t] = ohdg[t];
  if (b == 0 && t == 0) {
    float reg = 0.f;
    for (int m = 0; m < 4; ++m) {
      float s = 0.f;
      for (int bb = 0; bb < GBLK; ++bb) s += ssqP[m*GBLK + bb];
      reg += sqrtf(s);
    }
    S.scalf[1] = reg;
  }
  __syncthreads();

  // ================= batched pipelined main loop =================
  int va = 1, d_done = 0;
  unsigned T = 0;

  #pragma unroll 1
  for (;;) {
    const int tk3  = (int)(T & 3);
    const int idxD = (int)((T+1) & 3);
    const int idxC = (int)((T+2) & 3);
    const int idxB = (int)((T+3) & 3);
    const int v0D = S.bmeta[idxD][0], nD = S.bmeta[idxD][1];
    const int nC  = S.bmeta[idxC][1];
    const int nB  = S.bmeta[idxB][1];
    const bool canA = (va < NV);
    const int Kc = canA ? ((NV - va < K) ? (NV - va) : K) : 0;
    const int parR = (int)((T+1) & 1);
    const int parW = (int)(T & 1);

    // ---- phase 0: candidate staging + safety + D logits staging ----
    if (t < Kc*DEG) {
      int s = t >> 4, j = t & 15;
      int v = va + s;
      int u = adj[v*DEG + j];
      S.nbrs[tk3][s][j] = u;
      bool bad = false;
      float er = 0.f;
      if (u < v) {
        if (u > d_done) bad = true;
        else { float eh = eHvg[u]; er = (eh >= 0.f) ? eh : 0.2f*eh; }
      }
      S.e[s][j+1] = er;
      unsigned long long bm = __ballot(bad);
      if (j == 0) S.slotbad[s] = (int)((bm >> (((t >> 4) & 3)*16)) & 0xFFFFull);
    }
    if (t < K) S.e[t][0] = 0.f;
    for (int x = t; x < nD*260; x += TPB)
      S.logits[x] = logg[parR*(K*260) + x];
    __syncthreads();   // sync0

    int n = 0;
    while (n < Kc && S.slotbad[n] == 0) ++n;
    if (t == 0) { S.bmeta[tk3][0] = va; S.bmeta[tk3][1] = n; }

    // ---- phase 1: wave0 = attn softmax + serial D ; waves1-3 = B/C jobs ----
    if (wave == 0) {
      if (lane < n) {
        float m = 0.f;   // includes e[0]=0
        #pragma unroll
        for (int j = 1; j <= DEG; ++j) m = fmaxf(m, S.e[lane][j]);
        float ex[DEG+1]; float ssum = 0.f;
        #pragma unroll
        for (int j = 0; j <= DEG; ++j) { ex[j] = expf(S.e[lane][j] - m); ssum += ex[j]; }
        #pragma unroll
        for (int j = 0; j <= DEG; ++j) S.attn[lane][j] = ex[j] / ssum;
      }
      if (nD > 0) {
        int nused = S.scali[0];
        float lpp = S.scalf[0];
        float ppre[K];
        #pragma unroll
        for (int s2 = 0; s2 < K; ++s2) ppre[s2] = 0.f;
        if (b == 0 && lane < 32) {
          #pragma unroll
          for (int s2 = 0; s2 < K; ++s2)
            if (s2 < nD) ppre[s2] = eHpg[((v0D+s2)&63)*32 + lane];
        }
        #pragma unroll
        for (int s2 = 0; s2 < K; ++s2) {
          if (s2 >= nD) break;
          const int vD = v0D + s2;
          int nc[DEG];
          #pragma unroll
          for (int j = 0; j < DEG; ++j) nc[j] = (int)S.colors[S.nbrs[idxD][s2][j]] - 1;
          float sv[5]; float bmx = -INFINITY;
          #pragma unroll
          for (int p = 0; p < 5; ++p) {
            int idx = lane + p*64;
            float val = -INFINITY;
            if (idx < NL) {
              val = S.logits[s2*260 + idx];
              bool msk = (idx >= nused) && (idx < NPCC);
              #pragma unroll
              for (int j = 0; j < DEG; ++j) msk |= (idx == nc[j]);
              if (msk) val = -INFINITY;
            }
            sv[p] = val;
            bmx = fmaxf(bmx, val);
          }
          #pragma unroll
          for (int off = 1; off < 64; off <<= 1) bmx = fmaxf(bmx, __shfl_xor(bmx, off, 64));
          float ssum = 0.f;
          #pragma unroll
          for (int p = 0; p < 5; ++p) ssum += expf(sv[p] - bmx);
          #pragma unroll
          for (int off = 1; off < 64; off <<= 1) ssum += __shfl_xor(ssum, off, 64);
          float bp = -1.f; int bi = NL + 10;
          #pragma unroll
          for (int p = 0; p < 5; ++p) {
            int idx = lane + p*64;
            float pj = (idx < NL) ? (expf(sv[p] - bmx) / ssum) : -1.f;
            if (pj > bp) { bp = pj; bi = idx; }
          }
          #pragma unroll
          for (int off = 1; off < 64; off <<= 1) {
            float op = __shfl_xor(bp, off, 64);
            int   oi = __shfl_xor(bi, off, 64);
            if (op > bp || (op == bp && oi < bi)) { bp = op; bi = oi; }
          }
          const int isnew  = (bi == NPCC) ? 1 : 0;
          const int chosen = isnew ? nused : bi;
          nused += isnew;
          lpp += logf(bp + 1e-8f) - logf(1e-8f);
          if (lane == 0) {
            S.colors[vD] = (unsigned char)(chosen + 1);
            S.chosen[s2] = chosen;
          }
          if (b == 0) {
            float pp = (lane < 32) ? ppre[s2] : 0.f;
            #pragma unroll
            for (int off = 1; off < 32; off <<= 1) pp += __shfl_xor(pp, off, 64);
            if (lane == 0) eHvg[vD] = pp + S.ohdot[chosen];
          }
        }
        if (lane == 0) { S.scali[0] = nused; S.scalf[0] = lpp; }
      }
    } else {
      // waves 1-3: 12 groups; each job = one slot (B: fc2, C: fc3), x row in regs
      const int grp = (wave-1)*4 + g;
      const int tot = nB + nC;
      for (int job = grp; job < tot; job += 12) {
        const bool isB = (job < nB);
        const int s2 = isB ? job : job - nB;
        const float* xp = isB ? (h1g + parR*(K*512) + s2*512)
                              : (h2g + parR*(K*512) + s2*512);
        float4 xr[8];
        #pragma unroll
        for (int tt = 0; tt < 8; ++tt) xr[tt] = *(const float4*)&xp[j16*4 + tt*64];
        const int nr = isB ? nrows2 : nrows3;
        const float* wbase = isB ? S.fc2 : S.fc3;
        const float* bb    = isB ? S.fc2b : S.fc3b;
        for (int r = 0; r < 13; ++r) {
          if (r >= nr) break;
          float acc = 0.f;
          const float* wrow = wbase + r*512;
          #pragma unroll
          for (int tt = 0; tt < 8; ++tt) {
            float4 w4 = *(const float4*)&wrow[j16*4 + tt*64];
            acc += dot4(xr[tt], w4);
          }
          acc = red16_add(acc);
          if (j16 == 0) {
            if (isB) {
              float hvv = acc + bb[r];
              h2g[parW*(K*512) + s2*512 + base2 + r] = (hvv >= 0.f) ? hvv : 0.01f*hvv;
            } else {
              logg[parW*(K*260) + s2*260 + base3 + r] = acc + bb[r];
            }
          }
        }
      }
    }
    __syncthreads();   // sync1

    // ---- phase 2: W_oh fold (parallel) + gathers + aggregation ----
    {
      const int c0 = 2*t;
      // fold loads (threads 0..nD*16-1)
      const bool foldAct = (t < nD*16);
      const int fsp = t >> 4, fj = t & 15;
      float foldOld = 0.f, foldW = 0.f;
      if (foldAct) {
        foldOld = HF[(size_t)(v0D+fsp)*EMBD + kbase + fj];
        foldW   = W[(size_t)(512 + S.chosen[fsp])*512 + kbase + fj];
      }
      float2 hvA[16], hvB[16];
      if (n > 0) GATHER(0, hvA);
      if (n > 1) GATHER(1, hvB);
      if (foldAct) HF[(size_t)(v0D+fsp)*EMBD + kbase + fj] = foldOld + foldW;
      for (int s = 0; s < K; s += 2) {
        if (s >= n) break;
        AGG(s, hvA);
        if (s+2 < n) GATHER(s+2, hvA);
        if (s+1 < n) {
          AGG(s+1, hvB);
          if (s+3 < n) GATHER(s+3, hvB);
        }
      }
    }
    __syncthreads();   // sync2

    // ---- phase 3: batched fc1 + He for all n slots ----
    {
      const int r = wave*4 + g;
      float acc1[K], acc2[K];
      #pragma unroll
      for (int s = 0; s < K; ++s) { acc1[s] = 0.f; acc2[s] = 0.f; }
      const float* w1row = S.fc1 + r*512;
      const float* w2row = S.wembT + r*512;
      #pragma unroll
      for (int tt = 0; tt < 8; ++tt) {
        float4 w1 = *(const float4*)&w1row[j16*4 + tt*64];
        float4 w2 = *(const float4*)&w2row[j16*4 + tt*64];
        #pragma unroll
        for (int s = 0; s < K; ++s) {
          if (s < n) {
            float4 x4 = *(const float4*)&S.newe8[s][j16*4 + tt*64];
            acc1[s] += dot4(x4, w1);
            acc2[s] += dot4(x4, w2);
          }
        }
      }
      #pragma unroll
      for (int s = 0; s < K; ++s) {
        if (s < n) {
          float a1r = red16_add(acc1[s]);
          float a2r = red16_add(acc2[s]);
          if (j16 == 0) {
            float hvv = a1r + S.fc1b[r];
            h1g[parW*(K*512) + s*512 + kbase + r] = (hvv >= 0.f) ? hvv : 0.01f*hvv;
            HF[(size_t)(va+s)*EMBD + kbase + r] = a2r;
            S.hev[s][r] = a2r;
          }
        }
      }
    }
    __syncthreads();   // sync3

    // ---- eH partial publish + global barrier ----
    if (t < n) {
      float pp = 0.f;
      #pragma unroll
      for (int kk = 0; kk < 16; ++kk) pp += S.hev[t][kk] * S.a2[kbase + kk];
      eHpg[((va+t)&63)*32 + b] = pp;
    }
    __syncthreads();
    ++ep;
    if (t == 0) __hip_atomic_store(&flags[b*32], ep, __ATOMIC_RELEASE, __HIP_MEMORY_SCOPE_AGENT);
    if (t < 32) {
      while (__hip_atomic_load(&flags[t*32], __ATOMIC_RELAXED, __HIP_MEMORY_SCOPE_AGENT) < ep) { }
    }
    if (t == 0) (void)__hip_atomic_load(&flags[0], __ATOMIC_ACQUIRE, __HIP_MEMORY_SCOPE_AGENT);
    __syncthreads();

    // ---- advance ----
    if (nD > 0) d_done = v0D + nD - 1;
    va += n;
    ++T;
    if (d_done == NV-1) break;
    if (T > 12000u) break;   // safety: fail validation instead of hanging
  }

  // ================= output =================
  if (b == 0) {
    for (int i = t; i < NV; i += TPB) out[i] = (float)((int)S.colors[i] - 1);
    if (t == 0) {
      int bv = basep[0];
      int bl = (bv >= -100000 && bv <= 100000) ? bv : (int)__int_as_float(bv);
      float loss = ((float)(S.scali[0] - bl)) * S.scalf[0] / 8192.0f + 0.05f * S.scalf[1];
      out[NV] = loss;
    }
  }
}

extern "C" void kernel_launch(void* const* d_in, const int* in_sizes, int n_in,
                              void* d_out, int out_size, void* d_ws, size_t ws_size,
                              hipStream_t stream) {
  const int*   adj  = (const int*)d_in[0];
  const float* W    = (const float*)d_in[1];
  const float* av   = (const float*)d_in[2];
  const float* f1w  = (const float*)d_in[3];
  const float* f1b  = (const float*)d_in[4];
  const float* f2w  = (const float*)d_in[5];
  const float* f2b  = (const float*)d_in[6];
  const float* f3w  = (const float*)d_in[7];
  const float* f3b  = (const float*)d_in[8];
  const int*   bas  = (const int*)d_in[9];
  float* out = (float*)d_out;
  unsigned char* ws = (unsigned char*)d_ws;

  // zero barrier flags (workspace is poisoned 0xAA before every launch)
  (void)hipMemsetAsync(d_ws, 0, 8192, stream);
  (void)hipFuncSetAttribute((const void*)gc_kernel,
                      hipFuncAttributeMaxDynamicSharedMemorySize,
                      (int)sizeof(Smem));
  gc_kernel<<<dim3(GBLK), dim3(TPB), sizeof(Smem), stream>>>(
      adj, W, av, f1w, f1b, f2w, f2b, f3w, f3b, bas, out, ws);
}